// Round 1
// baseline (293.541 us; speedup 1.0000x reference)
//
#include <hip/hip_runtime.h>

typedef __bf16 bf16x8 __attribute__((ext_vector_type(8)));
typedef float  f32x4  __attribute__((ext_vector_type(4)));

#define MFMA(a,b,c) __builtin_amdgcn_mfma_f32_16x16x32_bf16((a),(b),(c),0,0,0)

__device__ __forceinline__ unsigned short f2bf(float f){
  unsigned u = __builtin_bit_cast(unsigned, f);
  u += 0x7fffu + ((u>>16)&1u);
  return (unsigned short)(u>>16);
}
__device__ __forceinline__ unsigned pack_bf2(float a, float b){
  return (unsigned)f2bf(a) | ((unsigned)f2bf(b)<<16);
}
__device__ __forceinline__ void gload_lds16(const void* g, void* l){
  __builtin_amdgcn_global_load_lds((__attribute__((address_space(1))) void*)(g),
                                   (__attribute__((address_space(3))) void*)(l), 16, 0, 0);
}

// ---------------- convert x (fp32 -> bf16), 16.7M elems ----------------
__global__ void k_cvt_x(const float* __restrict__ x, unsigned short* __restrict__ o){
  const size_t t = (size_t)blockIdx.x*256 + threadIdx.x;   // 1,048,576 threads
  #pragma unroll
  for (int i=0;i<4;i++){
    size_t idx = t + (size_t)i*1048576;                    // float4 index
    float4 f = ((const float4*)x)[idx];
    ((uint2*)o)[idx] = make_uint2(pack_bf2(f.x,f.y), pack_bf2(f.z,f.w));
  }
}

// ---------------- convert + transpose weights: W[K][N] fp32 -> WT[N][K] bf16 ----------------
__global__ void k_cvt_wT(const float* __restrict__ Wq, const float* __restrict__ Wk,
                         const float* __restrict__ Wv, const float* __restrict__ Wo,
                         unsigned short* __restrict__ wT){
  const int z = blockIdx.z;
  const float* W = (z==0)?Wq:(z==1)?Wk:(z==2)?Wv:Wo;
  unsigned short* out = wT + (size_t)z*1048576;
  __shared__ float tile[32][33];
  const int r0 = blockIdx.y*32, c0 = blockIdx.x*32;
  const int r = threadIdx.x>>5, c = threadIdx.x&31;
  #pragma unroll
  for (int i=0;i<4;i++) tile[r + i*8][c] = W[(size_t)(r0 + r + i*8)*1024 + c0 + c];
  __syncthreads();
  #pragma unroll
  for (int i=0;i<4;i++)
    out[(size_t)(c0 + r + i*8)*1024 + r0 + c] = f2bf(tile[c][r + i*8]);
}

// ---------------- GEMM core: C[128x128] = A[M,K] * WT[N,K]^T, bf16 in, fp32 acc ----------------
// MODE 0: QKV projection (z=blockIdx.z selects W/bias/output + layout). MODE 1: out proj -> fp32.
template<int MODE>
__global__ void k_gemm(const unsigned short* __restrict__ A,
                       const unsigned short* __restrict__ WT,
                       const float* __restrict__ bias0, const float* __restrict__ bias1,
                       const float* __restrict__ bias2,
                       unsigned short* __restrict__ q_ws, unsigned short* __restrict__ k_ws,
                       unsigned short* __restrict__ v_ws, float* __restrict__ outf)
{
  __shared__ unsigned short smem[16384];   // A tile [128][64]bf16 (16KB) + B tile (16KB), XOR-swizzled
  const int tid = threadIdx.x, lane = tid&63, wid = tid>>6;
  const int g = lane>>4, l15 = lane&15;
  const int wr = wid>>1, wc = wid&1;
  const int m0 = blockIdx.y<<7, n0 = blockIdx.x<<7;
  const int z = (MODE==0)? blockIdx.z : 3;
  const unsigned short* WTz = (MODE==0)? (WT + (size_t)blockIdx.z*1048576) : WT;

  f32x4 acc[4][4];
  #pragma unroll
  for (int i=0;i<4;i++)
    #pragma unroll
    for (int j=0;j<4;j++) acc[i][j] = f32x4{0.f,0.f,0.f,0.f};

  for (int kt=0;kt<16;kt++){
    __syncthreads();
    #pragma unroll
    for (int i=0;i<8;i++){
      const int chunk = wid*8 + i;           // 0..15 A, 16..31 B
      const int obase = chunk<<10;           // wave-uniform LDS dest
      const int o  = obase + lane*16;        // this lane's LDS byte (implied by HW)
      const int ro = o & 16383;
      const int r  = ro>>7, cb = ro&127;
      const int cs = cb ^ ((r&7)<<4);        // pre-swizzled source -> swizzled LDS (m173)
      const char* src;
      if (chunk < 16) src = (const char*)A   + ((size_t)(m0 + r)*2048) + (kt<<7) + cs;
      else            src = (const char*)WTz + ((size_t)(n0 + r)*2048) + (kt<<7) + cs;
      gload_lds16(src, (char*)smem + obase);
    }
    __syncthreads();
    #pragma unroll
    for (int ks=0;ks<2;ks++){
      bf16x8 af[4], bfr[4];
      const int cb = ks*64 + g*16;
      #pragma unroll
      for (int mf=0;mf<4;mf++){ const int m = wr*64 + mf*16 + l15;
        af[mf] = *(const bf16x8*)((const char*)smem + m*128 + (cb ^ ((m&7)<<4))); }
      #pragma unroll
      for (int nf=0;nf<4;nf++){ const int n = wc*64 + nf*16 + l15;
        bfr[nf] = *(const bf16x8*)((const char*)smem + 16384 + n*128 + (cb ^ ((n&7)<<4))); }
      #pragma unroll
      for (int mf=0;mf<4;mf++)
        #pragma unroll
        for (int nf=0;nf<4;nf++)
          acc[mf][nf] = MFMA(af[mf], bfr[nf], acc[mf][nf]);
    }
  }

  if constexpr (MODE==0){
    const float* bias = (z==0)? bias0 : (z==1)? bias1 : bias2;
    #pragma unroll
    for (int nf=0;nf<4;nf++){
      const int n = n0 + wc*64 + nf*16 + l15;
      const float bn = bias[n];
      const int h = n>>6, d = n&63;
      #pragma unroll
      for (int mf=0;mf<4;mf++){
        const int mb = m0 + wr*64 + mf*16 + g*4;
        if (z==2){
          // V stored transposed per window: [B,H,NW,D,W]; 4 regs = 4 consecutive w -> 8B store
          const int b = mb>>12, s = mb&4095, nw = s>>8, w0 = s&255;
          unsigned short pk0=f2bf(acc[mf][nf][0]+bn), pk1=f2bf(acc[mf][nf][1]+bn),
                         pk2=f2bf(acc[mf][nf][2]+bn), pk3=f2bf(acc[mf][nf][3]+bn);
          size_t idx = ((((size_t)(b*16+h)*16 + nw)*64 + d)<<8) + w0;
          *(ushort4*)(v_ws + idx) = make_ushort4(pk0,pk1,pk2,pk3);
        } else {
          unsigned short* dst = (z==0)? q_ws : k_ws;
          const float scale = (z==0)? 0.125f : 1.0f;   // fold 1/sqrt(D) into q
          #pragma unroll
          for (int r=0;r<4;r++){
            const int m = mb + r, b = m>>12, s = m&4095;
            dst[(((size_t)(b*16+h)*4096 + s)<<6) + d] = f2bf((acc[mf][nf][r]+bn)*scale);
          }
        }
      }
    }
  } else {
    #pragma unroll
    for (int nf=0;nf<4;nf++){
      const int n = n0 + wc*64 + nf*16 + l15;
      const float bn = bias0[n];
      #pragma unroll
      for (int mf=0;mf<4;mf++)
        #pragma unroll
        for (int r=0;r<4;r++){
          const int m = m0 + wr*64 + mf*16 + g*4 + r;
          outf[(size_t)m*1024 + n] = acc[mf][nf][r] + bn;
        }
    }
  }
}

// ---------------- windowed attention: 1 block per (b,h,window), 4 waves x 64 q-rows ----------------
__global__ __launch_bounds__(256,2) void k_attn(const unsigned short* __restrict__ qw,
                                                const unsigned short* __restrict__ kw,
                                                const unsigned short* __restrict__ vw,
                                                unsigned short* __restrict__ ow)
{
  __shared__ unsigned short Ks[2][4096];   // K sub-tile [64][64] bf16, swizzled, dbuf
  __shared__ unsigned short Vs[2][4096];   // V^T sub-tile [64 d][64 k] bf16, swizzled, dbuf
  __shared__ unsigned short Ps[4][4096];   // per-wave P [64][64] bf16, swizzled
  const int tid = threadIdx.x, lane = tid&63, wid = tid>>6;
  const int g = lane>>4, l15 = lane&15;
  const int bhn = blockIdx.x;
  const int nw = bhn&15, h = (bhn>>4)&15, b = bhn>>8;

  const size_t qkbase = ((size_t)((b*16+h)*4096 + nw*256))<<6;   // elems
  const unsigned short* Qg = qw + qkbase;
  const unsigned short* Kg = kw + qkbase;
  const unsigned short* Vg = vw + (((size_t)(b*16+h)*16 + nw)<<14);
  const float NEG_INF = -__builtin_inff();

  // Q fragments straight from global (read once)
  bf16x8 qa[4][2];
  #pragma unroll
  for (int qf=0;qf<4;qf++)
    #pragma unroll
    for (int ks=0;ks<2;ks++)
      qa[qf][ks] = *(const bf16x8*)((const char*)Qg + (wid*64 + qf*16 + l15)*128 + ks*64 + g*16);

  auto stage = [&](int kt, int bi){
    #pragma unroll
    for (int i=0;i<4;i++){
      const int chunk = wid*4 + i;        // 0..7 K, 8..15 V
      const int obase = (chunk&7)<<10;    // wave-uniform
      const int o = obase + lane*16;
      const int r = o>>7, cb = o&127;
      const int cs = cb ^ ((r&7)<<4);
      if (chunk < 8)
        gload_lds16((const char*)Kg + (kt*64 + r)*128 + cs, (char*)Ks[bi] + obase);
      else
        gload_lds16((const char*)Vg + r*512 + kt*128 + cs, (char*)Vs[bi] + obase);
    }
  };

  f32x4 oacc[4][4];
  float mrow[4][4], lrow[4][4];
  #pragma unroll
  for (int i=0;i<4;i++)
    #pragma unroll
    for (int j=0;j<4;j++){ oacc[i][j] = f32x4{0.f,0.f,0.f,0.f}; mrow[i][j] = NEG_INF; lrow[i][j] = 0.f; }

  stage(0,0);
  __syncthreads();
  for (int kt=0;kt<4;kt++){
    const int cur = kt&1;
    if (kt<3) stage(kt+1, cur^1);         // async prefetch, drained at end-of-iter barrier

    bf16x8 kb[4][2];
    #pragma unroll
    for (int kf=0;kf<4;kf++)
      #pragma unroll
      for (int ks=0;ks<2;ks++){
        const int kr = kf*16 + l15, cb = ks*64 + g*16;
        kb[kf][ks] = *(const bf16x8*)((const char*)Ks[cur] + kr*128 + (cb ^ ((kr&7)<<4)));
      }

    unsigned short* P = Ps[wid];
    #pragma unroll
    for (int qf=0;qf<4;qf++){
      f32x4 sfr[4];
      #pragma unroll
      for (int kf=0;kf<4;kf++){
        f32x4 zz = f32x4{0.f,0.f,0.f,0.f};
        zz = MFMA(qa[qf][0], kb[kf][0], zz);
        sfr[kf] = MFMA(qa[qf][1], kb[kf][1], zz);
      }
      #pragma unroll
      for (int r=0;r<4;r++){
        float t = fmaxf(fmaxf(sfr[0][r],sfr[1][r]), fmaxf(sfr[2][r],sfr[3][r]));
        t = fmaxf(t, __shfl_xor(t,1,64)); t = fmaxf(t, __shfl_xor(t,2,64));
        t = fmaxf(t, __shfl_xor(t,4,64)); t = fmaxf(t, __shfl_xor(t,8,64));
        const float mo = mrow[qf][r];
        const float mn = fmaxf(mo, t);
        const float alpha = __expf(mo - mn);     // exp(-inf)=0 on first tile
        float rs = 0.f;
        #pragma unroll
        for (int kf=0;kf<4;kf++){ float p = __expf(sfr[kf][r]-mn); sfr[kf][r] = p; rs += p; }
        rs += __shfl_xor(rs,1,64); rs += __shfl_xor(rs,2,64);
        rs += __shfl_xor(rs,4,64); rs += __shfl_xor(rs,8,64);
        lrow[qf][r] = lrow[qf][r]*alpha + rs;
        mrow[qf][r] = mn;
        #pragma unroll
        for (int df=0;df<4;df++) oacc[qf][df][r] *= alpha;
        const int prow = qf*16 + g*4 + r;
        const int sw = (prow&7)<<4;
        char* Pb = (char*)P + prow*128;
        #pragma unroll
        for (int kf=0;kf<4;kf++)
          *(unsigned short*)(Pb + (((kf*16 + l15)*2) ^ sw)) = f2bf(sfr[kf][r]);
      }
    }
    __builtin_amdgcn_sched_barrier(0);   // keep P writes before P reads (same-wave LDS in-order)

    bf16x8 vb[4][2];
    #pragma unroll
    for (int df=0;df<4;df++)
      #pragma unroll
      for (int ks=0;ks<2;ks++){
        const int d = df*16 + l15, cb = ks*64 + g*16;
        vb[df][ks] = *(const bf16x8*)((const char*)Vs[cur] + d*128 + (cb ^ ((d&7)<<4)));
      }
    #pragma unroll
    for (int qf=0;qf<4;qf++){
      const int pr = qf*16 + l15;
      const bf16x8 pa0 = *(const bf16x8*)((const char*)P + pr*128 + ((g*16)      ^ ((pr&7)<<4)));
      const bf16x8 pa1 = *(const bf16x8*)((const char*)P + pr*128 + ((64 + g*16) ^ ((pr&7)<<4)));
      #pragma unroll
      for (int df=0;df<4;df++){
        oacc[qf][df] = MFMA(pa0, vb[df][0], oacc[qf][df]);
        oacc[qf][df] = MFMA(pa1, vb[df][1], oacc[qf][df]);
      }
    }
    __syncthreads();   // all waves done with buf[cur]; prefetch (vmcnt) drained here
  }

  #pragma unroll
  for (int qf=0;qf<4;qf++)
    #pragma unroll
    for (int r=0;r<4;r++){
      const float inv = 1.f / lrow[qf][r];
      const int srow = nw*256 + wid*64 + qf*16 + g*4 + r;
      const size_t base = ((size_t)b*4096 + srow)*1024 + (size_t)h*64;
      #pragma unroll
      for (int df=0;df<4;df++)
        ow[base + df*16 + l15] = f2bf(oacc[qf][df][r]*inv);
    }
}

// ---------------- launch ----------------
extern "C" void kernel_launch(void* const* d_in, const int* in_sizes, int n_in,
                              void* d_out, int out_size, void* d_ws, size_t ws_size,
                              hipStream_t stream)
{
  const float* x  = (const float*)d_in[0];
  const float* Wq = (const float*)d_in[1];
  const float* bq = (const float*)d_in[2];
  const float* Wk = (const float*)d_in[3];
  const float* bk = (const float*)d_in[4];
  const float* Wv = (const float*)d_in[5];
  const float* bv = (const float*)d_in[6];
  const float* Wo = (const float*)d_in[7];
  const float* bo = (const float*)d_in[8];
  float* out = (float*)d_out;

  char* ws = (char*)d_ws;
  unsigned short* xbf  = (unsigned short*)(ws);                         // 32MB (reused as attn out)
  unsigned short* wT   = (unsigned short*)(ws + (size_t)32*1048576);    // 8MB, 4 x [1024][1024] bf16
  unsigned short* q_ws = (unsigned short*)(ws + (size_t)40*1048576);    // 32MB  [B,H,S,D]
  unsigned short* k_ws = (unsigned short*)(ws + (size_t)72*1048576);    // 32MB  [B,H,S,D]
  unsigned short* v_ws = (unsigned short*)(ws + (size_t)104*1048576);   // 32MB  [B,H,NW,D,W]
  unsigned short* obf  = xbf;                                           // attn output [B,S,E]

  k_cvt_x<<<4096,256,0,stream>>>(x, xbf);
  k_cvt_wT<<<dim3(32,32,4),256,0,stream>>>(Wq,Wk,Wv,Wo, wT);
  k_gemm<0><<<dim3(8,128,3),256,0,stream>>>(xbf, wT, bq,bk,bv, q_ws,k_ws,v_ws, nullptr);
  k_attn<<<1024,256,0,stream>>>(q_ws,k_ws,v_ws, obf);
  k_gemm<1><<<dim3(8,128,1),256,0,stream>>>(obf, wT + (size_t)3*1048576, bo,nullptr,nullptr,
                                            nullptr,nullptr,nullptr, out);
}

// Round 3
// 261.393 us; speedup vs baseline: 1.1230x; 1.1230x over previous
//
#include <hip/hip_runtime.h>

typedef __bf16 bf16x8 __attribute__((ext_vector_type(8)));
typedef float  f32x4  __attribute__((ext_vector_type(4)));

#define MFMA(a,b,c) __builtin_amdgcn_mfma_f32_16x16x32_bf16((a),(b),(c),0,0,0)

__device__ __forceinline__ unsigned short f2bf(float f){
  unsigned u = __builtin_bit_cast(unsigned, f);
  u += 0x7fffu + ((u>>16)&1u);
  return (unsigned short)(u>>16);
}
__device__ __forceinline__ unsigned pack_bf2(float a, float b){
  return (unsigned)f2bf(a) | ((unsigned)f2bf(b)<<16);
}
__device__ __forceinline__ void gload_lds16(const void* g, void* l){
  __builtin_amdgcn_global_load_lds((__attribute__((address_space(1))) void*)(g),
                                   (__attribute__((address_space(3))) void*)(l), 16, 0, 0);
}

// ---------------- convert x (fp32 -> bf16) ----------------
__global__ void k_cvt_x(const float* __restrict__ x, unsigned short* __restrict__ o){
  const size_t t = (size_t)blockIdx.x*256 + threadIdx.x;
  #pragma unroll
  for (int i=0;i<4;i++){
    size_t idx = t + (size_t)i*1048576;
    float4 f = ((const float4*)x)[idx];
    ((uint2*)o)[idx] = make_uint2(pack_bf2(f.x,f.y), pack_bf2(f.z,f.w));
  }
}

// ---------------- convert + transpose weights: W[K][N] fp32 -> WT[N][K] bf16 ----------------
__global__ void k_cvt_wT(const float* __restrict__ Wq, const float* __restrict__ Wk,
                         const float* __restrict__ Wv, const float* __restrict__ Wo,
                         unsigned short* __restrict__ wT){
  const int z = blockIdx.z;
  const float* W = (z==0)?Wq:(z==1)?Wk:(z==2)?Wv:Wo;
  unsigned short* out = wT + (size_t)z*1048576;
  __shared__ float tile[32][33];
  const int r0 = blockIdx.y*32, c0 = blockIdx.x*32;
  const int r = threadIdx.x>>5, c = threadIdx.x&31;
  #pragma unroll
  for (int i=0;i<4;i++) tile[r + i*8][c] = W[(size_t)(r0 + r + i*8)*1024 + c0 + c];
  __syncthreads();
  #pragma unroll
  for (int i=0;i<4;i++)
    out[(size_t)(c0 + r + i*8)*1024 + r0 + c] = f2bf(tile[c][r + i*8]);
}

// ---------------- 256^2 8-wave 4-phase/K-tile GEMM, counted vmcnt ----------------
// MODE 0: fused QKV (A[16384,1024] x WT[3072,1024]^T), epilogue -> q/k/v layouts.
// MODE 1: out projection -> fp32 + bias.
#define QUAD(MF0, KS) do { \
  _Pragma("unroll") \
  for (int mf_=0; mf_<4; ++mf_){ \
    _Pragma("unroll") \
    for (int nf_=0; nf_<4; ++nf_) \
      acc[MF0+mf_][nf_] = MFMA(aF[KS][MF0+mf_], bF[KS][nf_], acc[MF0+mf_][nf_]); \
  } } while(0)

template<int MODE>
__global__ __launch_bounds__(512,2) void k_gemm8(const unsigned short* __restrict__ A,
                       const unsigned short* __restrict__ Bm,
                       const float* __restrict__ bias0, const float* __restrict__ bias1,
                       const float* __restrict__ bias2,
                       unsigned short* __restrict__ q_ws, unsigned short* __restrict__ k_ws,
                       unsigned short* __restrict__ v_ws, float* __restrict__ outf)
{
  __shared__ char smem[131072];   // A dbuf 2x(2x16KB) @0, B dbuf @65536, XOR-swizzled
  const int tid = threadIdx.x, lane = tid&63, wid = tid>>6;
  const int g = lane>>4, l15 = lane&15;
  const int wr = wid>>2, wc = wid&3;      // 2 x 4 wave grid; wave tile 128x64

  constexpr int NBX = (MODE==0)? 12 : 4;
  constexpr int CPX = (MODE==0)? 96 : 32;   // (NBX*64)/8 per XCD
  const int flat = blockIdx.y*NBX + blockIdx.x;
  const int swz  = (flat&7)*CPX + (flat>>3);
  const int m0 = (swz/NBX)<<8, n0 = (swz%NBX)<<8;

  auto stage = [&](int h){
    const int t = h>>2, kind = h&3, hf = kind&1;
    char* ldst = smem + ((kind<2)?0:65536) + (t&1)*32768 + hf*16384 + wid*1024;
    const unsigned short* gbase = (kind<2)? A : Bm;
    const int row0 = ((kind<2)? m0 : n0) + hf*128;
    #pragma unroll
    for (int j=0;j<2;j++){
      const int o = (j*512 + tid)*16;
      const int r = o>>7, cb = o&127;
      const int cs = cb ^ ((r&7)<<4);
      gload_lds16((const char*)gbase + (size_t)(row0 + r)*2048 + t*128 + cs,
                  ldst + j*8192);
    }
  };

  f32x4 acc[8][4];
  #pragma unroll
  for (int i=0;i<8;i++)
    #pragma unroll
    for (int j=0;j<4;j++) acc[i][j] = f32x4{0.f,0.f,0.f,0.f};

  // prologue: tile0 all 4 halves + tile1 A-halves
  #pragma unroll
  for (int h=0;h<6;++h) stage(h);
  asm volatile("s_waitcnt vmcnt(4)" ::: "memory");
  __builtin_amdgcn_s_barrier();
  __builtin_amdgcn_sched_barrier(0);

  for (int t=0;t<16;++t){
    const char* Ab = smem + (t&1)*32768 + wr*16384;
    const char* Bb = smem + 65536 + (t&1)*32768 + (wc>>1)*16384;
    const int brow = (wc&1)*64;
    const int sw = (l15&7)<<4;
    bf16x8 aF[2][8], bF[2][4];

    // ---------- phase 0: all ks reads for mf0-3 + all B; MFMA mf0-3 ks0
    #pragma unroll
    for (int mf=0;mf<4;mf++){
      aF[0][mf] = *(const bf16x8*)(Ab + (mf*16+l15)*128 + ((g*16)    ^ sw));
      aF[1][mf] = *(const bf16x8*)(Ab + (mf*16+l15)*128 + ((64+g*16) ^ sw));
    }
    #pragma unroll
    for (int nf=0;nf<4;nf++){
      bF[0][nf] = *(const bf16x8*)(Bb + (brow+nf*16+l15)*128 + ((g*16)    ^ sw));
      bF[1][nf] = *(const bf16x8*)(Bb + (brow+nf*16+l15)*128 + ((64+g*16) ^ sw));
    }
    if (4*t+6 < 64) stage(4*t+6);       // B0 of tile t+1
    __builtin_amdgcn_sched_barrier(0);
    __builtin_amdgcn_s_barrier();
    __builtin_amdgcn_sched_barrier(0);
    __builtin_amdgcn_s_setprio(1);
    QUAD(0,0);
    __builtin_amdgcn_s_setprio(0);
    __builtin_amdgcn_sched_barrier(0);
    asm volatile("s_waitcnt lgkmcnt(0)" ::: "memory");
    __builtin_amdgcn_s_barrier();
    __builtin_amdgcn_sched_barrier(0);

    // ---------- phase 1: reads mf4-7 both ks; MFMA mf0-3 ks1
    #pragma unroll
    for (int mf=4;mf<8;mf++){
      aF[0][mf] = *(const bf16x8*)(Ab + (mf*16+l15)*128 + ((g*16)    ^ sw));
      aF[1][mf] = *(const bf16x8*)(Ab + (mf*16+l15)*128 + ((64+g*16) ^ sw));
    }
    if (4*t+7 < 64) stage(4*t+7);       // B1 of tile t+1
    __builtin_amdgcn_sched_barrier(0);
    __builtin_amdgcn_s_barrier();
    __builtin_amdgcn_sched_barrier(0);
    __builtin_amdgcn_s_setprio(1);
    QUAD(0,1);
    __builtin_amdgcn_s_setprio(0);
    __builtin_amdgcn_sched_barrier(0);
    asm volatile("s_waitcnt lgkmcnt(0)" ::: "memory");
    __builtin_amdgcn_s_barrier();
    __builtin_amdgcn_sched_barrier(0);

    // ---------- phase 2: no reads; MFMA mf4-7 ks0; stage A0 of t+2 (old A0 reads ended p1)
    if (4*t+8 < 64) stage(4*t+8);
    __builtin_amdgcn_sched_barrier(0);
    __builtin_amdgcn_s_barrier();
    __builtin_amdgcn_sched_barrier(0);
    __builtin_amdgcn_s_setprio(1);
    QUAD(4,0);
    __builtin_amdgcn_s_setprio(0);
    __builtin_amdgcn_sched_barrier(0);
    __builtin_amdgcn_s_barrier();
    __builtin_amdgcn_sched_barrier(0);

    // ---------- phase 3: no reads; MFMA mf4-7 ks1; stage A1 of t+2; counted vmcnt
    if (4*t+9 < 64) stage(4*t+9);
    __builtin_amdgcn_sched_barrier(0);
    __builtin_amdgcn_s_barrier();
    __builtin_amdgcn_sched_barrier(0);
    __builtin_amdgcn_s_setprio(1);
    QUAD(4,1);
    __builtin_amdgcn_s_setprio(0);
    __builtin_amdgcn_sched_barrier(0);
    if (t < 14)       asm volatile("s_waitcnt vmcnt(4)" ::: "memory");
    else if (t == 14) asm volatile("s_waitcnt vmcnt(0)" ::: "memory");
    __builtin_amdgcn_s_barrier();
    __builtin_amdgcn_sched_barrier(0);
  }

  // ---------------- epilogue ----------------
  if constexpr (MODE==0){
    const int z  = n0>>10;                 // 256 | 1024 -> uniform per block
    const int nE = n0 & 1023;
    const float* bias = (z==0)? bias0 : (z==1)? bias1 : bias2;
    #pragma unroll
    for (int nf=0;nf<4;nf++){
      const int ncol = nE + wc*64 + nf*16 + l15;
      const float bn = bias[ncol];
      const int h = ncol>>6, d = ncol&63;
      #pragma unroll
      for (int mf=0;mf<8;mf++){
        const int mb = m0 + wr*128 + mf*16 + g*4;
        if (z==2){
          const int b = mb>>12, s = mb&4095, nw = s>>8, w0 = s&255;
          unsigned short pk0=f2bf(acc[mf][nf][0]+bn), pk1=f2bf(acc[mf][nf][1]+bn),
                         pk2=f2bf(acc[mf][nf][2]+bn), pk3=f2bf(acc[mf][nf][3]+bn);
          size_t idx = ((((size_t)(b*16+h)*16 + nw)*64 + d)<<8) + w0;
          *(ushort4*)(v_ws + idx) = make_ushort4(pk0,pk1,pk2,pk3);
        } else {
          unsigned short* dst = (z==0)? q_ws : k_ws;
          const float scale = (z==0)? 0.125f : 1.0f;
          #pragma unroll
          for (int r=0;r<4;r++){
            const int m = mb + r, b = m>>12, s = m&4095;
            dst[(((size_t)(b*16+h)*4096 + s)<<6) + d] = f2bf((acc[mf][nf][r]+bn)*scale);
          }
        }
      }
    }
  } else {
    #pragma unroll
    for (int nf=0;nf<4;nf++){
      const int n = n0 + wc*64 + nf*16 + l15;
      const float bn = bias0[n];
      #pragma unroll
      for (int mf=0;mf<8;mf++)
        #pragma unroll
        for (int r=0;r<4;r++){
          const int m = m0 + wr*128 + mf*16 + g*4 + r;
          outf[(size_t)m*1024 + n] = acc[mf][nf][r] + bn;
        }
    }
  }
}

// ---------------- windowed attention: 1 block per (b,h,window), 4 waves x 64 q-rows ----------------
__global__ __launch_bounds__(256,2) void k_attn(const unsigned short* __restrict__ qw,
                                                const unsigned short* __restrict__ kw,
                                                const unsigned short* __restrict__ vw,
                                                unsigned short* __restrict__ ow)
{
  __shared__ unsigned short Ks[2][4096];
  __shared__ unsigned short Vs[2][4096];
  __shared__ unsigned short Ps[4][4096];
  const int tid = threadIdx.x, lane = tid&63, wid = tid>>6;
  const int g = lane>>4, l15 = lane&15;
  const int bhn = blockIdx.x;
  const int nw = bhn&15, h = (bhn>>4)&15, b = bhn>>8;

  const size_t qkbase = ((size_t)((b*16+h)*4096 + nw*256))<<6;
  const unsigned short* Qg = qw + qkbase;
  const unsigned short* Kg = kw + qkbase;
  const unsigned short* Vg = vw + (((size_t)(b*16+h)*16 + nw)<<14);
  const float NEG_INF = -__builtin_inff();

  bf16x8 qa[4][2];
  #pragma unroll
  for (int qf=0;qf<4;qf++)
    #pragma unroll
    for (int ks=0;ks<2;ks++)
      qa[qf][ks] = *(const bf16x8*)((const char*)Qg + (wid*64 + qf*16 + l15)*128 + ks*64 + g*16);

  auto stage = [&](int kt, int bi){
    #pragma unroll
    for (int i=0;i<4;i++){
      const int chunk = wid*4 + i;
      const int obase = (chunk&7)<<10;
      const int o = obase + lane*16;
      const int r = o>>7, cb = o&127;
      const int cs = cb ^ ((r&7)<<4);
      if (chunk < 8)
        gload_lds16((const char*)Kg + (kt*64 + r)*128 + cs, (char*)Ks[bi] + obase);
      else
        gload_lds16((const char*)Vg + r*512 + kt*128 + cs, (char*)Vs[bi] + obase);
    }
  };

  f32x4 oacc[4][4];
  float mrow[4][4], lrow[4][4];
  #pragma unroll
  for (int i=0;i<4;i++)
    #pragma unroll
    for (int j=0;j<4;j++){ oacc[i][j] = f32x4{0.f,0.f,0.f,0.f}; mrow[i][j] = NEG_INF; lrow[i][j] = 0.f; }

  stage(0,0);
  __syncthreads();
  for (int kt=0;kt<4;kt++){
    const int cur = kt&1;
    if (kt<3) stage(kt+1, cur^1);

    bf16x8 kb[4][2];
    #pragma unroll
    for (int kf=0;kf<4;kf++)
      #pragma unroll
      for (int ks=0;ks<2;ks++){
        const int kr = kf*16 + l15, cb = ks*64 + g*16;
        kb[kf][ks] = *(const bf16x8*)((const char*)Ks[cur] + kr*128 + (cb ^ ((kr&7)<<4)));
      }

    unsigned short* P = Ps[wid];
    #pragma unroll
    for (int qf=0;qf<4;qf++){
      f32x4 sfr[4];
      #pragma unroll
      for (int kf=0;kf<4;kf++){
        f32x4 zz = f32x4{0.f,0.f,0.f,0.f};
        zz = MFMA(qa[qf][0], kb[kf][0], zz);
        sfr[kf] = MFMA(qa[qf][1], kb[kf][1], zz);
      }
      #pragma unroll
      for (int r=0;r<4;r++){
        float t = fmaxf(fmaxf(sfr[0][r],sfr[1][r]), fmaxf(sfr[2][r],sfr[3][r]));
        t = fmaxf(t, __shfl_xor(t,1,64)); t = fmaxf(t, __shfl_xor(t,2,64));
        t = fmaxf(t, __shfl_xor(t,4,64)); t = fmaxf(t, __shfl_xor(t,8,64));
        const float mo = mrow[qf][r];
        const float mn = fmaxf(mo, t);
        const float alpha = __expf(mo - mn);
        float rs = 0.f;
        #pragma unroll
        for (int kf=0;kf<4;kf++){ float p = __expf(sfr[kf][r]-mn); sfr[kf][r] = p; rs += p; }
        rs += __shfl_xor(rs,1,64); rs += __shfl_xor(rs,2,64);
        rs += __shfl_xor(rs,4,64); rs += __shfl_xor(rs,8,64);
        lrow[qf][r] = lrow[qf][r]*alpha + rs;
        mrow[qf][r] = mn;
        #pragma unroll
        for (int df=0;df<4;df++) oacc[qf][df][r] *= alpha;
        const int prow = qf*16 + g*4 + r;
        const int sw = (prow&7)<<4;
        char* Pb = (char*)P + prow*128;
        #pragma unroll
        for (int kf=0;kf<4;kf++)
          *(unsigned short*)(Pb + (((kf*16 + l15)*2) ^ sw)) = f2bf(sfr[kf][r]);
      }
    }
    __builtin_amdgcn_sched_barrier(0);

    bf16x8 vb[4][2];
    #pragma unroll
    for (int df=0;df<4;df++)
      #pragma unroll
      for (int ks=0;ks<2;ks++){
        const int d = df*16 + l15, cb = ks*64 + g*16;
        vb[df][ks] = *(const bf16x8*)((const char*)Vs[cur] + d*128 + (cb ^ ((d&7)<<4)));
      }
    #pragma unroll
    for (int qf=0;qf<4;qf++){
      const int pr = qf*16 + l15;
      const bf16x8 pa0 = *(const bf16x8*)((const char*)P + pr*128 + ((g*16)      ^ ((pr&7)<<4)));
      const bf16x8 pa1 = *(const bf16x8*)((const char*)P + pr*128 + ((64 + g*16) ^ ((pr&7)<<4)));
      #pragma unroll
      for (int df=0;df<4;df++){
        oacc[qf][df] = MFMA(pa0, vb[df][0], oacc[qf][df]);
        oacc[qf][df] = MFMA(pa1, vb[df][1], oacc[qf][df]);
      }
    }
    __syncthreads();
  }

  #pragma unroll
  for (int qf=0;qf<4;qf++)
    #pragma unroll
    for (int r=0;r<4;r++){
      const float inv = 1.f / lrow[qf][r];
      const int srow = nw*256 + wid*64 + qf*16 + g*4 + r;
      const size_t base = ((size_t)b*4096 + srow)*1024 + (size_t)h*64;
      #pragma unroll
      for (int df=0;df<4;df++)
        ow[base + df*16 + l15] = f2bf(oacc[qf][df][r]*inv);
    }
}

// ---------------- launch ----------------
extern "C" void kernel_launch(void* const* d_in, const int* in_sizes, int n_in,
                              void* d_out, int out_size, void* d_ws, size_t ws_size,
                              hipStream_t stream)
{
  const float* x  = (const float*)d_in[0];
  const float* Wq = (const float*)d_in[1];
  const float* bq = (const float*)d_in[2];
  const float* Wk = (const float*)d_in[3];
  const float* bk = (const float*)d_in[4];
  const float* Wv = (const float*)d_in[5];
  const float* bv = (const float*)d_in[6];
  const float* Wo = (const float*)d_in[7];
  const float* bo = (const float*)d_in[8];
  float* out = (float*)d_out;

  char* ws = (char*)d_ws;
  unsigned short* xbf  = (unsigned short*)(ws);
  unsigned short* wT   = (unsigned short*)(ws + (size_t)32*1048576);
  unsigned short* q_ws = (unsigned short*)(ws + (size_t)40*1048576);
  unsigned short* k_ws = (unsigned short*)(ws + (size_t)72*1048576);
  unsigned short* v_ws = (unsigned short*)(ws + (size_t)104*1048576);
  unsigned short* obf  = xbf;

  k_cvt_x<<<4096,256,0,stream>>>(x, xbf);
  k_cvt_wT<<<dim3(32,32,4),256,0,stream>>>(Wq,Wk,Wv,Wo, wT);
  k_gemm8<0><<<dim3(12,64),512,0,stream>>>(xbf, wT, bq,bk,bv, q_ws,k_ws,v_ws, nullptr);
  k_attn<<<1024,256,0,stream>>>(q_ws,k_ws,v_ws, obf);
  k_gemm8<1><<<dim3(4,64),512,0,stream>>>(obf, wT + (size_t)3*1048576, bo,nullptr,nullptr,
                                          nullptr,nullptr,nullptr, out);
}

// Round 4
// 260.034 us; speedup vs baseline: 1.1289x; 1.0052x over previous
//
#include <hip/hip_runtime.h>

typedef __bf16 bf16x8 __attribute__((ext_vector_type(8)));
typedef float  f32x4  __attribute__((ext_vector_type(4)));

#define MFMA(a,b,c) __builtin_amdgcn_mfma_f32_16x16x32_bf16((a),(b),(c),0,0,0)
#define SB() __builtin_amdgcn_sched_barrier(0)

__device__ __forceinline__ unsigned short f2bf(float f){
  unsigned u = __builtin_bit_cast(unsigned, f);
  u += 0x7fffu + ((u>>16)&1u);
  return (unsigned short)(u>>16);
}
__device__ __forceinline__ unsigned pack_bf2(float a, float b){
  return (unsigned)f2bf(a) | ((unsigned)f2bf(b)<<16);
}
__device__ __forceinline__ void gload_lds16(const void* g, void* l){
  __builtin_amdgcn_global_load_lds((__attribute__((address_space(1))) void*)(g),
                                   (__attribute__((address_space(3))) void*)(l), 16, 0, 0);
}

// ---------------- convert x (fp32 -> bf16) ----------------
__global__ void k_cvt_x(const float* __restrict__ x, unsigned short* __restrict__ o){
  const size_t t = (size_t)blockIdx.x*256 + threadIdx.x;
  #pragma unroll
  for (int i=0;i<4;i++){
    size_t idx = t + (size_t)i*1048576;
    float4 f = ((const float4*)x)[idx];
    ((uint2*)o)[idx] = make_uint2(pack_bf2(f.x,f.y), pack_bf2(f.z,f.w));
  }
}

// ---------------- convert + transpose weights: W[K][N] fp32 -> WT[N][K] bf16 ----------------
__global__ void k_cvt_wT(const float* __restrict__ Wq, const float* __restrict__ Wk,
                         const float* __restrict__ Wv, const float* __restrict__ Wo,
                         unsigned short* __restrict__ wT){
  const int z = blockIdx.z;
  const float* W = (z==0)?Wq:(z==1)?Wk:(z==2)?Wv:Wo;
  unsigned short* out = wT + (size_t)z*1048576;
  __shared__ float tile[32][33];
  const int r0 = blockIdx.y*32, c0 = blockIdx.x*32;
  const int r = threadIdx.x>>5, c = threadIdx.x&31;
  #pragma unroll
  for (int i=0;i<4;i++) tile[r + i*8][c] = W[(size_t)(r0 + r + i*8)*1024 + c0 + c];
  __syncthreads();
  #pragma unroll
  for (int i=0;i<4;i++)
    out[(size_t)(c0 + r + i*8)*1024 + r0 + c] = f2bf(tile[c][r + i*8]);
}

// ---------------- 256^2 8-wave 4-phase/K-tile GEMM, balanced reads, counted vmcnt ----------------
// Stage slots: p0 B0(t+1), p1 B1(t+1), p3 A0+A1(t+2).  Reads 8/8/8/0 per phase.
#define QUAD16(AF, BF, MF0) do { \
  _Pragma("unroll") \
  for (int mf_=0; mf_<4; ++mf_){ \
    _Pragma("unroll") \
    for (int nf_=0; nf_<4; ++nf_) \
      acc[MF0+mf_][nf_] = MFMA(AF[mf_], BF[nf_], acc[MF0+mf_][nf_]); \
  } } while(0)

template<int MODE>
__global__ __launch_bounds__(512,2) void k_gemm8(const unsigned short* __restrict__ A,
                       const unsigned short* __restrict__ Bm,
                       const float* __restrict__ bias0, const float* __restrict__ bias1,
                       const float* __restrict__ bias2,
                       unsigned short* __restrict__ q_ws, unsigned short* __restrict__ k_ws,
                       unsigned short* __restrict__ v_ws, float* __restrict__ outf)
{
  __shared__ char smem[131072];   // A dbuf 2x32KB @0, B dbuf @65536, XOR-swizzled
  const int tid = threadIdx.x, lane = tid&63, wid = tid>>6;
  const int g = lane>>4, l15 = lane&15;
  const int wr = wid>>2, wc = wid&3;      // 2 x 4 wave grid; wave tile 128x64

  constexpr int NBX = (MODE==0)? 12 : 4;
  constexpr int CPX = (MODE==0)? 96 : 32;
  const int flat = blockIdx.y*NBX + blockIdx.x;
  const int swz  = (flat&7)*CPX + (flat>>3);
  const int m0 = (swz/NBX)<<8, n0 = (swz%NBX)<<8;

  // stage one 128-row half-tile (16KB): isA selects operand, tt the K-tile, hf the half
  auto stageH = [&](int isA, int tt, int hf){
    char* ldst = smem + (isA?0:65536) + (tt&1)*32768 + hf*16384 + wid*1024;
    const unsigned short* gbase = isA? A : Bm;
    const int row0 = (isA? m0 : n0) + hf*128;
    #pragma unroll
    for (int j=0;j<2;j++){
      const int o = (j*512 + tid)*16;
      const int r = o>>7, cb = o&127;
      const int cs = cb ^ ((r&7)<<4);
      gload_lds16((const char*)gbase + (size_t)(row0 + r)*2048 + (tt<<7) + cs,
                  ldst + j*8192);
    }
  };

  f32x4 acc[8][4];
  #pragma unroll
  for (int i=0;i<8;i++)
    #pragma unroll
    for (int j=0;j<4;j++) acc[i][j] = f32x4{0.f,0.f,0.f,0.f};

  // prologue: A(0), B(0), A(1) — vmcnt(4) leaves A(1) in flight
  stageH(1,0,0); stageH(1,0,1);
  stageH(0,0,0); stageH(0,0,1);
  stageH(1,1,0); stageH(1,1,1);
  asm volatile("s_waitcnt vmcnt(4)" ::: "memory");
  __builtin_amdgcn_s_barrier();
  SB();

  const int sw = (l15&7)<<4;
  for (int t=0;t<16;++t){
    const char* Ab = smem + (t&1)*32768 + wr*16384;
    const char* Bb = smem + 65536 + (t&1)*32768 + (wc>>1)*16384;
    const int brow = (wc&1)*64;
    bf16x8 aK0[4], aK1[4], bK0[4], bK1[4];

    // ---------- phase 0: read A ks0 mf0-3 + B ks0; stage B0(t+1); MFMA (0,ks0)
    #pragma unroll
    for (int mf=0;mf<4;mf++)
      aK0[mf] = *(const bf16x8*)(Ab + (mf*16+l15)*128 + ((g*16) ^ sw));
    #pragma unroll
    for (int nf=0;nf<4;nf++)
      bK0[nf] = *(const bf16x8*)(Bb + (brow+nf*16+l15)*128 + ((g*16) ^ sw));
    if (t+1 < 16) stageH(0, t+1, 0);
    SB();
    __builtin_amdgcn_s_barrier();
    asm volatile("s_waitcnt lgkmcnt(0)" ::: "memory");
    SB();
    __builtin_amdgcn_s_setprio(1);
    QUAD16(aK0, bK0, 0);
    __builtin_amdgcn_s_setprio(0);
    SB();
    __builtin_amdgcn_s_barrier();
    SB();

    // ---------- phase 1: read A ks1 mf0-3 + B ks1; stage B1(t+1); MFMA (0,ks1)
    #pragma unroll
    for (int mf=0;mf<4;mf++)
      aK1[mf] = *(const bf16x8*)(Ab + (mf*16+l15)*128 + ((64+g*16) ^ sw));
    #pragma unroll
    for (int nf=0;nf<4;nf++)
      bK1[nf] = *(const bf16x8*)(Bb + (brow+nf*16+l15)*128 + ((64+g*16) ^ sw));
    if (t+1 < 16) stageH(0, t+1, 1);
    SB();
    __builtin_amdgcn_s_barrier();
    asm volatile("s_waitcnt lgkmcnt(0)" ::: "memory");
    SB();
    __builtin_amdgcn_s_setprio(1);
    QUAD16(aK1, bK1, 0);
    __builtin_amdgcn_s_setprio(0);
    SB();
    __builtin_amdgcn_s_barrier();
    SB();

    // ---------- phase 2: read A mf4-7 both ks; MFMA (4,ks0)
    #pragma unroll
    for (int mf=0;mf<4;mf++)
      aK0[mf] = *(const bf16x8*)(Ab + ((4+mf)*16+l15)*128 + ((g*16) ^ sw));
    #pragma unroll
    for (int mf=0;mf<4;mf++)
      aK1[mf] = *(const bf16x8*)(Ab + ((4+mf)*16+l15)*128 + ((64+g*16) ^ sw));
    SB();
    __builtin_amdgcn_s_barrier();
    asm volatile("s_waitcnt lgkmcnt(0)" ::: "memory");
    SB();
    __builtin_amdgcn_s_setprio(1);
    QUAD16(aK0, bK0, 4);
    __builtin_amdgcn_s_setprio(0);
    SB();
    __builtin_amdgcn_s_barrier();
    SB();

    // ---------- phase 3: stage A0+A1(t+2) (A(t) reads ended p2, barrier-separated); MFMA (4,ks1)
    if (t+2 < 16){ stageH(1, t+2, 0); stageH(1, t+2, 1); }
    SB();
    __builtin_amdgcn_s_barrier();
    SB();
    __builtin_amdgcn_s_setprio(1);
    QUAD16(aK1, bK1, 4);
    __builtin_amdgcn_s_setprio(0);
    SB();
    if (t < 14)       asm volatile("s_waitcnt vmcnt(4)" ::: "memory");
    else if (t == 14) asm volatile("s_waitcnt vmcnt(0)" ::: "memory");
    __builtin_amdgcn_s_barrier();
    SB();
  }

  // ---------------- epilogue ----------------
  if constexpr (MODE==0){
    const int z  = n0>>10;
    const int nE = n0 & 1023;
    const float* bias = (z==0)? bias0 : (z==1)? bias1 : bias2;
    #pragma unroll
    for (int nf=0;nf<4;nf++){
      const int ncol = nE + wc*64 + nf*16 + l15;
      const float bn = bias[ncol];
      const int h = ncol>>6, d = ncol&63;
      #pragma unroll
      for (int mf=0;mf<8;mf++){
        const int mb = m0 + wr*128 + mf*16 + g*4;
        if (z==2){
          const int b = mb>>12, s = mb&4095, nw = s>>8, w0 = s&255;
          unsigned short pk0=f2bf(acc[mf][nf][0]+bn), pk1=f2bf(acc[mf][nf][1]+bn),
                         pk2=f2bf(acc[mf][nf][2]+bn), pk3=f2bf(acc[mf][nf][3]+bn);
          size_t idx = ((((size_t)(b*16+h)*16 + nw)*64 + d)<<8) + w0;
          *(ushort4*)(v_ws + idx) = make_ushort4(pk0,pk1,pk2,pk3);
        } else {
          unsigned short* dst = (z==0)? q_ws : k_ws;
          const float scale = (z==0)? 0.125f : 1.0f;
          #pragma unroll
          for (int r=0;r<4;r++){
            const int m = mb + r, b = m>>12, s = m&4095;
            dst[(((size_t)(b*16+h)*4096 + s)<<6) + d] = f2bf((acc[mf][nf][r]+bn)*scale);
          }
        }
      }
    }
  } else {
    #pragma unroll
    for (int nf=0;nf<4;nf++){
      const int n = n0 + wc*64 + nf*16 + l15;
      const float bn = bias0[n];
      #pragma unroll
      for (int mf=0;mf<8;mf++)
        #pragma unroll
        for (int r=0;r<4;r++){
          const int m = m0 + wr*128 + mf*16 + g*4 + r;
          outf[(size_t)m*1024 + n] = acc[mf][nf][r] + bn;
        }
    }
  }
}

// ---------------- windowed attention: 1 block per (b,h,window), 4 waves x 64 q-rows ----------------
__global__ __launch_bounds__(256,2) void k_attn(const unsigned short* __restrict__ qw,
                                                const unsigned short* __restrict__ kw,
                                                const unsigned short* __restrict__ vw,
                                                unsigned short* __restrict__ ow)
{
  __shared__ unsigned short Ks[2][4096];
  __shared__ unsigned short Vs[2][4096];
  __shared__ unsigned short Ps[4][4096];
  const int tid = threadIdx.x, lane = tid&63, wid = tid>>6;
  const int g = lane>>4, l15 = lane&15;
  const int bhn = blockIdx.x;
  const int nw = bhn&15, h = (bhn>>4)&15, b = bhn>>8;

  const size_t qkbase = ((size_t)((b*16+h)*4096 + nw*256))<<6;
  const unsigned short* Qg = qw + qkbase;
  const unsigned short* Kg = kw + qkbase;
  const unsigned short* Vg = vw + (((size_t)(b*16+h)*16 + nw)<<14);
  const float NEG_INF = -__builtin_inff();

  bf16x8 qa[4][2];
  #pragma unroll
  for (int qf=0;qf<4;qf++)
    #pragma unroll
    for (int ks=0;ks<2;ks++)
      qa[qf][ks] = *(const bf16x8*)((const char*)Qg + (wid*64 + qf*16 + l15)*128 + ks*64 + g*16);

  auto stage = [&](int kt, int bi){
    #pragma unroll
    for (int i=0;i<4;i++){
      const int chunk = wid*4 + i;
      const int obase = (chunk&7)<<10;
      const int o = obase + lane*16;
      const int r = o>>7, cb = o&127;
      const int cs = cb ^ ((r&7)<<4);
      if (chunk < 8)
        gload_lds16((const char*)Kg + (kt*64 + r)*128 + cs, (char*)Ks[bi] + obase);
      else
        gload_lds16((const char*)Vg + r*512 + kt*128 + cs, (char*)Vs[bi] + obase);
    }
  };

  f32x4 oacc[4][4];
  float mrow[4][4], lrow[4][4];
  #pragma unroll
  for (int i=0;i<4;i++)
    #pragma unroll
    for (int j=0;j<4;j++){ oacc[i][j] = f32x4{0.f,0.f,0.f,0.f}; mrow[i][j] = NEG_INF; lrow[i][j] = 0.f; }

  stage(0,0);
  __syncthreads();
  for (int kt=0;kt<4;kt++){
    const int cur = kt&1;
    if (kt<3) stage(kt+1, cur^1);

    bf16x8 kb[4][2];
    #pragma unroll
    for (int kf=0;kf<4;kf++)
      #pragma unroll
      for (int ks=0;ks<2;ks++){
        const int kr = kf*16 + l15, cb = ks*64 + g*16;
        kb[kf][ks] = *(const bf16x8*)((const char*)Ks[cur] + kr*128 + (cb ^ ((kr&7)<<4)));
      }

    unsigned short* P = Ps[wid];
    #pragma unroll
    for (int qf=0;qf<4;qf++){
      f32x4 sfr[4];
      #pragma unroll
      for (int kf=0;kf<4;kf++){
        f32x4 zz = f32x4{0.f,0.f,0.f,0.f};
        zz = MFMA(qa[qf][0], kb[kf][0], zz);
        sfr[kf] = MFMA(qa[qf][1], kb[kf][1], zz);
      }
      #pragma unroll
      for (int r=0;r<4;r++){
        float t = fmaxf(fmaxf(sfr[0][r],sfr[1][r]), fmaxf(sfr[2][r],sfr[3][r]));
        t = fmaxf(t, __shfl_xor(t,1,64)); t = fmaxf(t, __shfl_xor(t,2,64));
        t = fmaxf(t, __shfl_xor(t,4,64)); t = fmaxf(t, __shfl_xor(t,8,64));
        const float mo = mrow[qf][r];
        const float mn = fmaxf(mo, t);
        const float alpha = __expf(mo - mn);
        float rs = 0.f;
        #pragma unroll
        for (int kf=0;kf<4;kf++){ float p = __expf(sfr[kf][r]-mn); sfr[kf][r] = p; rs += p; }
        rs += __shfl_xor(rs,1,64); rs += __shfl_xor(rs,2,64);
        rs += __shfl_xor(rs,4,64); rs += __shfl_xor(rs,8,64);
        lrow[qf][r] = lrow[qf][r]*alpha + rs;
        mrow[qf][r] = mn;
        #pragma unroll
        for (int df=0;df<4;df++) oacc[qf][df][r] *= alpha;
        const int prow = qf*16 + g*4 + r;
        const int sw = (prow&7)<<4;
        char* Pb = (char*)P + prow*128;
        #pragma unroll
        for (int kf=0;kf<4;kf++)
          *(unsigned short*)(Pb + (((kf*16 + l15)*2) ^ sw)) = f2bf(sfr[kf][r]);
      }
    }
    __builtin_amdgcn_sched_barrier(0);

    bf16x8 vb[4][2];
    #pragma unroll
    for (int df=0;df<4;df++)
      #pragma unroll
      for (int ks=0;ks<2;ks++){
        const int d = df*16 + l15, cb = ks*64 + g*16;
        vb[df][ks] = *(const bf16x8*)((const char*)Vs[cur] + d*128 + (cb ^ ((d&7)<<4)));
      }
    #pragma unroll
    for (int qf=0;qf<4;qf++){
      const int pr = qf*16 + l15;
      const bf16x8 pa0 = *(const bf16x8*)((const char*)P + pr*128 + ((g*16)      ^ ((pr&7)<<4)));
      const bf16x8 pa1 = *(const bf16x8*)((const char*)P + pr*128 + ((64 + g*16) ^ ((pr&7)<<4)));
      #pragma unroll
      for (int df=0;df<4;df++){
        oacc[qf][df] = MFMA(pa0, vb[df][0], oacc[qf][df]);
        oacc[qf][df] = MFMA(pa1, vb[df][1], oacc[qf][df]);
      }
    }
    __syncthreads();
  }

  #pragma unroll
  for (int qf=0;qf<4;qf++)
    #pragma unroll
    for (int r=0;r<4;r++){
      const float inv = 1.f / lrow[qf][r];
      const int srow = nw*256 + wid*64 + qf*16 + g*4 + r;
      const size_t base = ((size_t)b*4096 + srow)*1024 + (size_t)h*64;
      #pragma unroll
      for (int df=0;df<4;df++)
        ow[base + df*16 + l15] = f2bf(oacc[qf][df][r]*inv);
    }
}

// ---------------- launch ----------------
extern "C" void kernel_launch(void* const* d_in, const int* in_sizes, int n_in,
                              void* d_out, int out_size, void* d_ws, size_t ws_size,
                              hipStream_t stream)
{
  const float* x  = (const float*)d_in[0];
  const float* Wq = (const float*)d_in[1];
  const float* bq = (const float*)d_in[2];
  const float* Wk = (const float*)d_in[3];
  const float* bk = (const float*)d_in[4];
  const float* Wv = (const float*)d_in[5];
  const float* bv = (const float*)d_in[6];
  const float* Wo = (const float*)d_in[7];
  const float* bo = (const float*)d_in[8];
  float* out = (float*)d_out;

  char* ws = (char*)d_ws;
  unsigned short* xbf  = (unsigned short*)(ws);
  unsigned short* wT   = (unsigned short*)(ws + (size_t)32*1048576);
  unsigned short* q_ws = (unsigned short*)(ws + (size_t)40*1048576);
  unsigned short* k_ws = (unsigned short*)(ws + (size_t)72*1048576);
  unsigned short* v_ws = (unsigned short*)(ws + (size_t)104*1048576);
  unsigned short* obf  = xbf;

  k_cvt_x<<<4096,256,0,stream>>>(x, xbf);
  k_cvt_wT<<<dim3(32,32,4),256,0,stream>>>(Wq,Wk,Wv,Wo, wT);
  k_gemm8<0><<<dim3(12,64),512,0,stream>>>(xbf, wT, bq,bk,bv, q_ws,k_ws,v_ws, nullptr);
  k_attn<<<1024,256,0,stream>>>(q_ws,k_ws,v_ws, obf);
  k_gemm8<1><<<dim3(4,64),512,0,stream>>>(obf, wT + (size_t)3*1048576, bo,nullptr,nullptr,
                                          nullptr,nullptr,nullptr, out);
}